// Round 5
// baseline (75.952 us; speedup 1.0000x reference)
//
#include <hip/hip_runtime.h>
#include <math.h>

#define B_ 2
#define SQ_ 1024
#define SK_ 1024
#define D_ 64
#define DV_ 64
#define QB 4
#define KSPLIT 2
#define KTILE (SK_ / KSPLIT)  // 512 keys per block
#define CE 80.0f              // p = exp(CE - dist); shared bias, no max pass
#define QSCALE 2048.0f
#define QINV (1.0f / 2048.0f)

// d_ws layout (u32 units):
//   wsq  [0,         65536)  q  u16-packed pairs [B][SQ][32]
//   wsk  [65536,    131072)  k  u16-packed pairs [B][SK][32]
//   wsv  [131072,   196608)  v  bf16-packed pairs [B][SK][32]
//   ws_o [196608,   458752)  fp32 partial O [row=B*SQ][KSPLIT][64]
//   ws_l [458752,   462848)  fp32 partial l [row][KSPLIT]

__device__ inline unsigned int pk2(float x, float y) {
  int xi = (int)rintf(fminf(fmaxf(x, -15.9f), 15.9f) * QSCALE) + 32768;
  int yi = (int)rintf(fminf(fmaxf(y, -15.9f), 15.9f) * QSCALE) + 32768;
  return (unsigned int)(xi & 0xffff) | ((unsigned int)yi << 16);
}

__device__ inline unsigned int bfp2(float lo, float hi) {  // bf16 RNE pair
  union { float f; unsigned int u; } a, b;
  a.f = lo; b.f = hi;
  unsigned int ua = a.u + 0x7fff + ((a.u >> 16) & 1);
  unsigned int ub = b.u + 0x7fff + ((b.u >> 16) & 1);
  return (ua >> 16) | (ub & 0xffff0000u);
}

// ---- Kernel 1: quantize q,k -> u16 ; v -> bf16. 49152 threads. ----
__global__ __launch_bounds__(256) void convert_qkv(
    const float* __restrict__ qg, const float* __restrict__ kg,
    const float* __restrict__ vg, unsigned int* __restrict__ ws) {
  const int t = blockIdx.x * 256 + threadIdx.x;
  uint4 r;
  if (t < 32768) {  // q or k -> u16 fixed point
    const float4* s4 = (t < 16384) ? (const float4*)qg : (const float4*)kg;
    const int idx = t & 16383;
    float4 a = s4[idx * 2], b = s4[idx * 2 + 1];
    r.x = pk2(a.x, a.y); r.y = pk2(a.z, a.w);
    r.z = pk2(b.x, b.y); r.w = pk2(b.z, b.w);
  } else {  // v -> bf16
    const int idx = t - 32768;
    float4 a = ((const float4*)vg)[idx * 2], b = ((const float4*)vg)[idx * 2 + 1];
    r.x = bfp2(a.x, a.y); r.y = bfp2(a.z, a.w);
    r.z = bfp2(b.x, b.y); r.w = bfp2(b.z, b.w);
  }
  ((uint4*)ws)[t] = r;
}

__device__ inline int slot(int kl) { return kl ^ ((kl >> 5) & 3); }

// ---- Kernel 2: partial attention. grid = B*(SQ/QB)*KSPLIT = 1024 x 256. ----
__global__ __launch_bounds__(256, 4) void manh_main(
    const unsigned int* __restrict__ ws, const int* __restrict__ maskg,
    float* __restrict__ ws_o, float* __restrict__ ws_l) {
  __shared__ float4 p4s[KTILE];      // 8 KB probs (swizzled slots)
  __shared__ float pv[4][QB][DV_];   // 4 KB per-wave PV partials
  __shared__ float4 redl[4];         // per-wave l partials

  const unsigned int* wsq = ws;
  const unsigned int* wsk = ws + 65536;
  const unsigned int* wsv = ws + 131072;

  const int tid = threadIdx.x;
  const int wid = tid >> 6;
  const int split = blockIdx.x & 1;
  const int qgrp = (blockIdx.x >> 1) & 255;
  const int b = blockIdx.x >> 9;
  const int q0 = qgrp * QB;
  const int kbase = split * KTILE;

  const int kq = tid >> 2;  // key within 64-key pass
  const int qt = tid & 3;   // dim quarter (16 dims = 2 uint4)

  // q fragments: this thread's dim-quarter of 4 query rows (32 VGPRs)
  const uint4* qrow4 = (const uint4*)(wsq + ((size_t)b * SQ_ + q0) * 32);
  uint4 qr[QB][2];
#pragma unroll
  for (int q = 0; q < QB; ++q) {
    qr[q][0] = qrow4[q * 8 + qt * 2];
    qr[q][1] = qrow4[q * 8 + qt * 2 + 1];
  }

  const uint4* krow4 = (const uint4*)(wsk + (size_t)b * SK_ * 32);
  const int* mb = maskg + (size_t)b * SK_;

  // ---- Phase 1: 8 passes x 64 keys, 4 lanes/key, reg double-buffered K ----
  float lsum[QB] = {0.f, 0.f, 0.f, 0.f};
  uint4 kc0 = krow4[(size_t)(kbase + kq) * 8 + qt * 2];
  uint4 kc1 = krow4[(size_t)(kbase + kq) * 8 + qt * 2 + 1];
#pragma unroll 1
  for (int p = 0; p < 8; ++p) {
    const int keyn = kbase + (((p + 1) & 7) << 6) + kq;
    uint4 kn0 = krow4[(size_t)keyn * 8 + qt * 2];
    uint4 kn1 = krow4[(size_t)keyn * 8 + qt * 2 + 1];
    unsigned int d[QB] = {0u, 0u, 0u, 0u};
#pragma unroll
    for (int q = 0; q < QB; ++q) {
      d[q] = __builtin_amdgcn_sad_u16(qr[q][0].x, kc0.x, d[q]);
      d[q] = __builtin_amdgcn_sad_u16(qr[q][0].y, kc0.y, d[q]);
      d[q] = __builtin_amdgcn_sad_u16(qr[q][0].z, kc0.z, d[q]);
      d[q] = __builtin_amdgcn_sad_u16(qr[q][0].w, kc0.w, d[q]);
      d[q] = __builtin_amdgcn_sad_u16(qr[q][1].x, kc1.x, d[q]);
      d[q] = __builtin_amdgcn_sad_u16(qr[q][1].y, kc1.y, d[q]);
      d[q] = __builtin_amdgcn_sad_u16(qr[q][1].z, kc1.z, d[q]);
      d[q] = __builtin_amdgcn_sad_u16(qr[q][1].w, kc1.w, d[q]);
    }
#pragma unroll
    for (int q = 0; q < QB; ++q) {
      d[q] += __shfl_xor(d[q], 1, 64);
      d[q] += __shfl_xor(d[q], 2, 64);
    }
    if ((tid & 3) == (p & 3)) {  // one owner lane per key
      const int kl = (p << 6) + kq;
      const int mk = mb[kbase + kl];
      float4 e;
      e.x = mk ? __expf(fmaf(-(float)d[0], QINV, CE)) : 0.f;
      e.y = mk ? __expf(fmaf(-(float)d[1], QINV, CE)) : 0.f;
      e.z = mk ? __expf(fmaf(-(float)d[2], QINV, CE)) : 0.f;
      e.w = mk ? __expf(fmaf(-(float)d[3], QINV, CE)) : 0.f;
      p4s[slot(kl)] = e;
      lsum[0] += e.x; lsum[1] += e.y; lsum[2] += e.z; lsum[3] += e.w;
    }
    kc0 = kn0; kc1 = kn1;
  }
#pragma unroll
  for (int off = 32; off > 0; off >>= 1)
#pragma unroll
    for (int q = 0; q < QB; ++q) lsum[q] += __shfl_down(lsum[q], off, 64);
  if ((tid & 63) == 0)
    redl[wid] = make_float4(lsum[0], lsum[1], lsum[2], lsum[3]);
  __syncthreads();  // covers p4s + redl

  // ---- Phase 2: PV over 512 keys. 16 dv-cols x 16 chunks x 32 keys ----
  const int col = tid & 15;    // 4 dims (2 bf16-pair u32s)
  const int chunk = tid >> 4;  // 16 chunks of 32 keys
  const uint2* vb2 = (const uint2*)(wsv + (size_t)b * SK_ * 32);
  float4 acc[QB];
#pragma unroll
  for (int q = 0; q < QB; ++q) acc[q] = make_float4(0.f, 0.f, 0.f, 0.f);
#pragma unroll 8
  for (int t = 0; t < 32; ++t) {
    const int kl = chunk * 32 + t;
    uint2 vr = vb2[(size_t)(kbase + kl) * 16 + col];
    float4 pw = p4s[slot(kl)];  // 16-lane broadcast; swizzle debanks chunks
    union { unsigned int u; float f; } v0, v1, v2, v3;
    v0.u = vr.x << 16; v1.u = vr.x & 0xffff0000u;
    v2.u = vr.y << 16; v3.u = vr.y & 0xffff0000u;
    acc[0].x += pw.x * v0.f; acc[0].y += pw.x * v1.f;
    acc[0].z += pw.x * v2.f; acc[0].w += pw.x * v3.f;
    acc[1].x += pw.y * v0.f; acc[1].y += pw.y * v1.f;
    acc[1].z += pw.y * v2.f; acc[1].w += pw.y * v3.f;
    acc[2].x += pw.z * v0.f; acc[2].y += pw.z * v1.f;
    acc[2].z += pw.z * v2.f; acc[2].w += pw.z * v3.f;
    acc[3].x += pw.w * v0.f; acc[3].y += pw.w * v1.f;
    acc[3].z += pw.w * v2.f; acc[3].w += pw.w * v3.f;
  }
  // combine 4 chunks within each wave (lane bits 4,5)
#pragma unroll
  for (int q = 0; q < QB; ++q) {
    acc[q].x += __shfl_xor(acc[q].x, 16, 64);
    acc[q].y += __shfl_xor(acc[q].y, 16, 64);
    acc[q].z += __shfl_xor(acc[q].z, 16, 64);
    acc[q].w += __shfl_xor(acc[q].w, 16, 64);
    acc[q].x += __shfl_xor(acc[q].x, 32, 64);
    acc[q].y += __shfl_xor(acc[q].y, 32, 64);
    acc[q].z += __shfl_xor(acc[q].z, 32, 64);
    acc[q].w += __shfl_xor(acc[q].w, 32, 64);
  }
  if ((tid & 63) < 16) {
#pragma unroll
    for (int q = 0; q < QB; ++q) ((float4*)&pv[wid][q][0])[col] = acc[q];
  }
  __syncthreads();

  // epilogue: 256 threads = 4 q x 64 dims; write split partials
  const int q2 = tid >> 6;
  const int d2 = tid & 63;
  float o = pv[0][q2][d2] + pv[1][q2][d2] + pv[2][q2][d2] + pv[3][q2][d2];
  const size_t row = (size_t)b * SQ_ + q0 + q2;
  ws_o[(row * KSPLIT + split) * DV_ + d2] = o;
  if (d2 == 0) {
    float l = redl[0].x * 0.f;  // keep type; recompute below
    const float* rl = (const float*)redl;
    l = rl[0 * 4 + q2] + rl[1 * 4 + q2] + rl[2 * 4 + q2] + rl[3 * 4 + q2];
    ws_l[row * KSPLIT + split] = l;
  }
}

// ---- Kernel 3: combine splits (shared bias -> partials just add) ----
__global__ __launch_bounds__(256) void manh_combine(
    const float* __restrict__ ws_o, const float* __restrict__ ws_l,
    float* __restrict__ outg) {
  const int gid = blockIdx.x * 256 + threadIdx.x;
  const int r = gid >> 6;
  const int d = gid & 63;
  const float l = ws_l[r * 2] + ws_l[r * 2 + 1];
  const float o = ws_o[(r * 2) * DV_ + d] + ws_o[(r * 2 + 1) * DV_ + d];
  outg[(size_t)r * DV_ + d] = o / l;
}

extern "C" void kernel_launch(void* const* d_in, const int* in_sizes, int n_in,
                              void* d_out, int out_size, void* d_ws,
                              size_t ws_size, hipStream_t stream) {
  const float* q = (const float*)d_in[0];
  const float* k = (const float*)d_in[1];
  const float* v = (const float*)d_in[2];
  const int* mask = (const int*)d_in[3];
  float* out = (float*)d_out;

  unsigned int* ws = (unsigned int*)d_ws;
  float* ws_o = (float*)(ws + 196608);
  float* ws_l = (float*)(ws + 458752);

  convert_qkv<<<dim3(192), dim3(256), 0, stream>>>(q, k, v, ws);
  manh_main<<<dim3(B_ * (SQ_ / QB) * KSPLIT), dim3(256), 0, stream>>>(
      ws, mask, ws_o, ws_l);
  manh_combine<<<dim3(B_ * SQ_ * DV_ / 256), dim3(256), 0, stream>>>(
      ws_o, ws_l, out);
}